// Round 10
// baseline (160.112 us; speedup 1.0000x reference)
//
#include <hip/hip_runtime.h>
#include <hip/hip_bf16.h>

// Fused Swin window attention for MI355X (gfx950) — round 10: 4 blocks/CU.
// r9 (head-partition, 44KB LDS, 3 blocks/CU) was still latency-bound with all
// pipes <25%. VGPR=84 leaves headroom; the only occupancy cap is LDS.
// r10 squeezes LDS to exactly 40,960 B -> 4 blocks/CU (16 waves/CU), and
// 2048 blocks = exactly 2 clean dispatch rounds:
//   * x/oh region UNPADDED (stride 256) + XOR bank swizzle col ^= (l15&7)<<3
//     — swizzle INSTEAD of padding (r7 failed composing both). All b128/b64
//     accesses verified at the bank floor; write key == read key == KEY(row).
//   * per-wave scratch 2.5KB -> 2KB: one 16x64 swizzled buffer serves q/k
//     round-trips (16-row sub-passes), v-transpose, and P. In-wave LDS RAW
//     is ordered by the in-order DS pipe; no extra barriers.
//   * total = 64*256*2 + 4*1024*2 = 40,960 B; 4 blocks x 40,960 = 163,840
//     = exactly the 160 KiB pool.

typedef __attribute__((ext_vector_type(8))) short bf16x8;
typedef __attribute__((ext_vector_type(4))) float f32x4;

__device__ __forceinline__ f32x4 mfma16(bf16x8 a, bf16x8 b, f32x4 c) {
  return __builtin_amdgcn_mfma_f32_16x16x32_bf16(a, b, c, 0, 0, 0);
}

__device__ __forceinline__ unsigned short f2bf(float f) {
  __hip_bfloat16 h = __float2bfloat16(f);
  return *reinterpret_cast<unsigned short*>(&h);
}

__device__ __forceinline__ uint2 pack4(float a, float b, float c, float d) {
  union { unsigned short u[4]; uint2 v; } pk;
  pk.u[0] = f2bf(a); pk.u[1] = f2bf(b); pk.u[2] = f2bf(c); pk.u[3] = f2bf(d);
  return pk.v;
}

#define LOG2E 1.4426950408889634f
#define EXPSCALE (0.17677669529663687f * 1.4426950408889634f)

// LDS (ushort elements): x/oh 64x256 (swizzled, no pad) + 4 x 16x64 scratch.
#define XO 256
#define OFF_RT 16384
#define RT_ELEMS 1024
#define SMEM_ELTS 20480   // 40,960 bytes -> 4 blocks/CU

// Weight tiled layout: elem(n,k) -> ((((n>>4)*8+(k>>5))*4+((k>>3)&3))*16+(n&15))*8+(k&7)
__global__ void prep_kernel(const float* __restrict__ w_qkv,
                            const float* __restrict__ w_out,
                            const float* __restrict__ pos_emb,
                            unsigned short* __restrict__ wqkvT,
                            unsigned short* __restrict__ woutT,
                            float* __restrict__ bias64) {
  const int stride = gridDim.x * blockDim.x;
  const int tid = blockIdx.x * blockDim.x + threadIdx.x;
  for (int i = tid; i < 768 * 256; i += stride) {
    int n = i >> 8, k = i & 255;
    int off = ((((n >> 4) * 8 + (k >> 5)) * 4 + ((k >> 3) & 3)) * 16 + (n & 15)) * 8 + (k & 7);
    wqkvT[off] = f2bf(w_qkv[k * 768 + n]);
  }
  for (int i = tid; i < 256 * 256; i += stride) {
    int n = i >> 8, k = i & 255;
    int off = ((((n >> 4) * 8 + (k >> 5)) * 4 + ((k >> 3) & 3)) * 16 + (n & 15)) * 8 + (k & 7);
    woutT[off] = f2bf(w_out[k * 256 + n]);
  }
  for (int i = tid; i < 64 * 64; i += stride) {
    int a = i >> 6, b = i & 63;
    int d0 = (b >> 3) - (a >> 3) + 7;
    int d1 = (b & 7) - (a & 7) + 7;
    bias64[i] = pos_emb[d0 * 15 + d1] * LOG2E;   // pre-scaled for exp2
  }
}

// 64px x 32col GEMM slice from swizzled x region.
// SWAP=true: acc = mfma(w, x) -> D[feat][px]. SWAP=false -> D[px][feat].
template <bool SWAP>
__device__ __forceinline__ void gemm32(f32x4 (&acc)[4][2],
                                       const unsigned short* __restrict__ a_lds,
                                       const unsigned short* __restrict__ wT,
                                       int col0, int l15, int lq, int key) {
  const f32x4 zero4 = {0.f, 0.f, 0.f, 0.f};
#pragma unroll
  for (int rt = 0; rt < 4; ++rt)
#pragma unroll
    for (int ct = 0; ct < 2; ++ct) acc[rt][ct] = zero4;
#pragma unroll
  for (int kk = 0; kk < 8; ++kk) {
    bf16x8 a[4], b[2];
#pragma unroll
    for (int rt = 0; rt < 4; ++rt)
      a[rt] = *(const bf16x8*)&a_lds[(rt * 16 + l15) * XO + ((kk * 32 + lq * 8) ^ key)];
#pragma unroll
    for (int ct = 0; ct < 2; ++ct)
      b[ct] = *(const bf16x8*)&wT[((((col0 >> 4) + ct) * 8 + kk) * 4 + lq) * 128 + l15 * 8];
#pragma unroll
    for (int rt = 0; rt < 4; ++rt)
#pragma unroll
      for (int ct = 0; ct < 2; ++ct)
        acc[rt][ct] = SWAP ? mfma16(b[ct], a[rt], acc[rt][ct])
                           : mfma16(a[rt], b[ct], acc[rt][ct]);
  }
}

__global__ __launch_bounds__(256, 4)
void winattn_kernel(const float* __restrict__ x,
                    const unsigned short* __restrict__ wqkvT,
                    const unsigned short* __restrict__ woutT,
                    const float* __restrict__ bias64,
                    const float* __restrict__ b_out,
                    float* __restrict__ out) {
  __shared__ unsigned short smem[SMEM_ELTS];

  const int tid = threadIdx.x;
  const int lane = tid & 63;
  const int w = tid >> 6;
  const int l15 = lane & 15;
  const int lq = lane >> 4;
  const int key = (l15 & 7) << 3;      // swizzle key for row ≡ l15 (mod 16)

  const int bid = blockIdx.x;
  const int win = bid & 255;
  const int img = bid >> 8;
  const int wy = win >> 4, wx = win & 15;

  unsigned short* x_lds  = smem;                 // phase 1-2: x; phase 3-4: oh
  unsigned short* oh_lds = smem;
  unsigned short* rt_buf = smem + OFF_RT + w * RT_ELEMS;   // wave-private 16x64

  const f32x4 zero4 = {0.f, 0.f, 0.f, 0.f};
  const size_t img_base = (size_t)img * 128 * 128 * 256;

  // ---------- phase 1: stage x window -> bf16 LDS (coalesced, swizzled) ----------
  {
#pragma unroll
    for (int r = 0; r < 16; ++r) {
      int p = r * 4 + w;                 // pixel 0..63 (whole wave on one row)
      const float* src = x + img_base +
          (((size_t)(wy * 8 + (p >> 3)) * 128) + (wx * 8 + (p & 7))) * 256 + lane * 4;
      float4 v4 = *(const float4*)src;
      *(uint2*)&x_lds[p * XO + ((lane * 4) ^ ((p & 7) << 3))] =
          pack4(v4.x, v4.y, v4.z, v4.w);
    }
  }
  __syncthreads();   // bar1

  // ---------- phase 2: q/k/v for this wave's 2 heads, all wave-local ----------
  // qf/kf[rt][hh]: A/B-frag, (px rt*16+l15, feat hh*32+lq*8..+8)
  // vf[ft][h2][hh]: A-frag of vT, (feat hh*32+ft*16+l15, kv px h2*32+lq*8..+8)
  bf16x8 qf[4][2], kf[4][2], vf[2][2][2];
  {
    f32x4 acc[4][2];
#pragma unroll
    for (int hh = 0; hh < 2; ++hh) {    // q chunk (swapped: feat rows, px cols)
      gemm32<true>(acc, x_lds, wqkvT, w * 64 + hh * 32, l15, lq, key);
#pragma unroll
      for (int rt = 0; rt < 4; ++rt) {  // 16-row sub-pass per px tile
#pragma unroll
        for (int ct = 0; ct < 2; ++ct)
          *(uint2*)&rt_buf[l15 * 64 + ((ct * 16 + lq * 4) ^ key)] =
              pack4(acc[rt][ct][0], acc[rt][ct][1], acc[rt][ct][2], acc[rt][ct][3]);
        qf[rt][hh] = *(const bf16x8*)&rt_buf[l15 * 64 + ((lq * 8) ^ key)];
      }
    }
#pragma unroll
    for (int hh = 0; hh < 2; ++hh) {    // k chunk
      gemm32<true>(acc, x_lds, wqkvT, 256 + w * 64 + hh * 32, l15, lq, key);
#pragma unroll
      for (int rt = 0; rt < 4; ++rt) {
#pragma unroll
        for (int ct = 0; ct < 2; ++ct)
          *(uint2*)&rt_buf[l15 * 64 + ((ct * 16 + lq * 4) ^ key)] =
              pack4(acc[rt][ct][0], acc[rt][ct][1], acc[rt][ct][2], acc[rt][ct][3]);
        kf[rt][hh] = *(const bf16x8*)&rt_buf[l15 * 64 + ((lq * 8) ^ key)];
      }
    }
#pragma unroll
    for (int hh = 0; hh < 2; ++hh) {    // v chunk (normal: px rows, feat cols)
      gemm32<false>(acc, x_lds, wqkvT, 512 + w * 64 + hh * 32, l15, lq, key);
#pragma unroll
      for (int h2 = 0; h2 < 2; ++h2)    // kv-px half
#pragma unroll
        for (int ct = 0; ct < 2; ++ct) {   // feat tile; transpose via scratch
#pragma unroll
          for (int rr = 0; rr < 2; ++rr)
            *(uint2*)&rt_buf[l15 * 64 + ((rr * 16 + lq * 4) ^ key)] =
                pack4(acc[h2 * 2 + rr][ct][0], acc[h2 * 2 + rr][ct][1],
                      acc[h2 * 2 + rr][ct][2], acc[h2 * 2 + rr][ct][3]);
          vf[ct][h2][hh] = *(const bf16x8*)&rt_buf[l15 * 64 + ((lq * 8) ^ key)];
        }
    }
  }
  __syncthreads();   // bar2: all x reads done -> oh region (overlays x) safe

  // ---------- phase 3: attention for heads {2w, 2w+1}, all 64 pixels ----------
#pragma unroll
  for (int it = 0; it < 4; ++it) {
    f32x4 bias4[4];
#pragma unroll
    for (int jt = 0; jt < 4; ++jt)
      bias4[jt] = *(const f32x4*)&bias64[(it * 16 + l15) * 64 + jt * 16 + lq * 4];
#pragma unroll
    for (int hh = 0; hh < 2; ++hh) {
      // S^T = mfma(k, q): D[kv jt*16+lq*4+r][q px it*16+l15]
      f32x4 s[4];
#pragma unroll
      for (int jt = 0; jt < 4; ++jt)
        s[jt] = mfma16(kf[jt][hh], qf[it][hh], zero4);
      // p = exp2(s*ES + bias); row-sum over kv (regs + lq lanes)
      float rs = 0.f;
#pragma unroll
      for (int jt = 0; jt < 4; ++jt)
#pragma unroll
        for (int r = 0; r < 4; ++r) {
          s[jt][r] = __builtin_amdgcn_exp2f(s[jt][r] * EXPSCALE + bias4[jt][r]);
          rs += s[jt][r];
        }
      rs += __shfl_xor(rs, 16);
      rs += __shfl_xor(rs, 32);
      const float rinv = __builtin_amdgcn_rcpf(rs);

      // P -> wave-private scratch (P[q l15][kv]), packed b64, swizzled
#pragma unroll
      for (int jt = 0; jt < 4; ++jt)
        *(uint2*)&rt_buf[l15 * 64 + ((jt * 16 + lq * 4) ^ key)] =
            pack4(s[jt][0], s[jt][1], s[jt][2], s[jt][3]);
      const bf16x8 ap0 = *(const bf16x8*)&rt_buf[l15 * 64 + ((lq * 8) ^ key)];
      const bf16x8 ap1 = *(const bf16x8*)&rt_buf[l15 * 64 + ((32 + lq * 8) ^ key)];

      // oh^T = mfma(vT, P^T): D[feat ft*16+lq*4+r][q px it*16+l15]
      f32x4 o0 = mfma16(vf[0][0][hh], ap0, zero4);
      o0 = mfma16(vf[0][1][hh], ap1, o0);
      f32x4 o1 = mfma16(vf[1][0][hh], ap0, zero4);
      o1 = mfma16(vf[1][1][hh], ap1, o1);

      // normalize + stage oh (shared region, swizzled), packed b64
      *(uint2*)&oh_lds[(it * 16 + l15) * XO + ((w * 64 + hh * 32 + lq * 4) ^ key)] =
          pack4(o0[0] * rinv, o0[1] * rinv, o0[2] * rinv, o0[3] * rinv);
      *(uint2*)&oh_lds[(it * 16 + l15) * XO + ((w * 64 + hh * 32 + 16 + lq * 4) ^ key)] =
          pack4(o1[0] * rinv, o1[1] * rinv, o1[2] * rinv, o1[3] * rinv);
    }
  }
  __syncthreads();   // bar3: oh complete

  // ---------- phase 4: out-proj, one K=256 GEMM (swapped) + epilogue ----------
  {
    f32x4 ACC[4][4];
#pragma unroll
    for (int rt = 0; rt < 4; ++rt)
#pragma unroll
      for (int ct = 0; ct < 4; ++ct) ACC[rt][ct] = zero4;
#pragma unroll
    for (int kk = 0; kk < 8; ++kk) {
      bf16x8 a[4], b[4];
#pragma unroll
      for (int rt = 0; rt < 4; ++rt)
        a[rt] = *(const bf16x8*)&oh_lds[(rt * 16 + l15) * XO + ((kk * 32 + lq * 8) ^ key)];
#pragma unroll
      for (int ct = 0; ct < 4; ++ct)
        b[ct] = *(const bf16x8*)&woutT[(((w * 4 + ct) * 8 + kk) * 4 + lq) * 128 + l15 * 8];
#pragma unroll
      for (int rt = 0; rt < 4; ++rt)
#pragma unroll
        for (int ct = 0; ct < 4; ++ct)
          ACC[rt][ct] = mfma16(b[ct], a[rt], ACC[rt][ct]);   // D[ofeat][px]
    }
    // epilogue: D rows = ofeat w*64+ct*16+lq*4+r, cols = px rt*16+l15
#pragma unroll
    for (int rt = 0; rt < 4; ++rt) {
      const int p = rt * 16 + l15;
      float* orow = out + img_base +
          (((size_t)(wy * 8 + (p >> 3)) * 128) + (wx * 8 + (p & 7))) * 256;
#pragma unroll
      for (int ct = 0; ct < 4; ++ct) {
        const int n0 = w * 64 + ct * 16 + lq * 4;
        const f32x4 bo4 = *(const f32x4*)&b_out[n0];
        f32x4 st;
#pragma unroll
        for (int r = 0; r < 4; ++r) st[r] = ACC[rt][ct][r] + bo4[r];
        *(f32x4*)(orow + n0) = st;
      }
    }
  }
}

extern "C" void kernel_launch(void* const* d_in, const int* in_sizes, int n_in,
                              void* d_out, int out_size, void* d_ws, size_t ws_size,
                              hipStream_t stream) {
  const float* x       = (const float*)d_in[0];
  const float* w_qkv   = (const float*)d_in[1];
  const float* pos_emb = (const float*)d_in[2];
  const float* w_out   = (const float*)d_in[3];
  const float* b_out   = (const float*)d_in[4];
  float* out = (float*)d_out;

  unsigned short* wqkvT = (unsigned short*)d_ws;
  unsigned short* woutT = wqkvT + 768 * 256;
  float* bias64 = (float*)(woutT + 256 * 256);

  prep_kernel<<<96, 256, 0, stream>>>(w_qkv, w_out, pos_emb, wqkvT, woutT, bias64);
  winattn_kernel<<<2048, 256, 0, stream>>>(x, wqkvT, woutT, bias64, b_out, out);
}

// Round 11
// 132.329 us; speedup vs baseline: 1.2099x; 1.2099x over previous
//
#include <hip/hip_runtime.h>
#include <hip/hip_bf16.h>

// Fused Swin window attention for MI355X (gfx950) — round 11: r9 + ILP.
// r10 lesson: 4 blocks/CU needs VGPR<=128, but the fragment-resident design
// (qf/kf/vf = 96 VGPR) can't fit -> spills (WRITE 131->285MB), dur regressed.
// r11 reverts to r9's 3 blocks/CU (44KB LDS, 170 VGPR budget) and spends the
// register headroom (r9 used only 84) on shortening per-wave latency chains:
//   * phase 2: dual-accumulator chunk interleave — each scratch round-trip
//     (in-order DS queue WAR) is covered by the next chunk's 16 MFMAs.
//   * phase 3: software pipeline — S(i+1)+exp+rowsum computed between P(i)
//     write and readback (r5's trick re-derived for head-partition).
//   * phase 4: ping-pong prefetch of a/b frags (kk+1 during kk's MFMAs).
// Everything else byte-identical to r9 (which passed at 116.5us).

typedef __attribute__((ext_vector_type(8))) short bf16x8;
typedef __attribute__((ext_vector_type(4))) float f32x4;

__device__ __forceinline__ f32x4 mfma16(bf16x8 a, bf16x8 b, f32x4 c) {
  return __builtin_amdgcn_mfma_f32_16x16x32_bf16(a, b, c, 0, 0, 0);
}

__device__ __forceinline__ unsigned short f2bf(float f) {
  __hip_bfloat16 h = __float2bfloat16(f);
  return *reinterpret_cast<unsigned short*>(&h);
}

__device__ __forceinline__ uint2 pack4(float a, float b, float c, float d) {
  union { unsigned short u[4]; uint2 v; } pk;
  pk.u[0] = f2bf(a); pk.u[1] = f2bf(b); pk.u[2] = f2bf(c); pk.u[3] = f2bf(d);
  return pk.v;
}

#define LOG2E 1.4426950408889634f
#define EXPSCALE (0.17677669529663687f * 1.4426950408889634f)

// LDS layout (ushort elements); row strides multiples of 8 elem (16B) for b128.
#define XO  264           // x / oh region row stride (64 rows)
#define RTS 40            // per-wave RT scratch row stride (32 rows used)
#define PS  72            // P scratch row stride (16 rows)
#define RT_ELEMS 1280     // per-wave scratch: 32x40 (covers P's 16x72=1152)
#define OFF_RT 16896      // 64*264
#define SMEM_ELTS 22016   // 16896 + 4*1280 = 44,032 B -> 3 blocks/CU

// Weight tiled layout: elem(n,k) -> ((((n>>4)*8+(k>>5))*4+((k>>3)&3))*16+(n&15))*8+(k&7)
__global__ void prep_kernel(const float* __restrict__ w_qkv,
                            const float* __restrict__ w_out,
                            const float* __restrict__ pos_emb,
                            unsigned short* __restrict__ wqkvT,
                            unsigned short* __restrict__ woutT,
                            float* __restrict__ bias64) {
  const int stride = gridDim.x * blockDim.x;
  const int tid = blockIdx.x * blockDim.x + threadIdx.x;
  for (int i = tid; i < 768 * 256; i += stride) {
    int n = i >> 8, k = i & 255;
    int off = ((((n >> 4) * 8 + (k >> 5)) * 4 + ((k >> 3) & 3)) * 16 + (n & 15)) * 8 + (k & 7);
    wqkvT[off] = f2bf(w_qkv[k * 768 + n]);
  }
  for (int i = tid; i < 256 * 256; i += stride) {
    int n = i >> 8, k = i & 255;
    int off = ((((n >> 4) * 8 + (k >> 5)) * 4 + ((k >> 3) & 3)) * 16 + (n & 15)) * 8 + (k & 7);
    woutT[off] = f2bf(w_out[k * 256 + n]);
  }
  for (int i = tid; i < 64 * 64; i += stride) {
    int a = i >> 6, b = i & 63;
    int d0 = (b >> 3) - (a >> 3) + 7;
    int d1 = (b & 7) - (a & 7) + 7;
    bias64[i] = pos_emb[d0 * 15 + d1] * LOG2E;   // pre-scaled for exp2
  }
}

// 64px x 32col GEMM slice. SWAP=true: acc = mfma(w, x) -> (feat row, px col).
// SWAP=false: acc = mfma(x, w) -> (px row, feat col).
template <bool SWAP>
__device__ __forceinline__ void gemm32(f32x4 (&acc)[4][2],
                                       const unsigned short* __restrict__ a_lds,
                                       const unsigned short* __restrict__ wT,
                                       int col0, int l15, int lq) {
  const f32x4 zero4 = {0.f, 0.f, 0.f, 0.f};
#pragma unroll
  for (int rt = 0; rt < 4; ++rt)
#pragma unroll
    for (int ct = 0; ct < 2; ++ct) acc[rt][ct] = zero4;
#pragma unroll
  for (int kk = 0; kk < 8; ++kk) {
    bf16x8 a[4], b[2];
#pragma unroll
    for (int rt = 0; rt < 4; ++rt)
      a[rt] = *(const bf16x8*)&a_lds[(rt * 16 + l15) * XO + kk * 32 + lq * 8];
#pragma unroll
    for (int ct = 0; ct < 2; ++ct)
      b[ct] = *(const bf16x8*)&wT[((((col0 >> 4) + ct) * 8 + kk) * 4 + lq) * 128 + l15 * 8];
#pragma unroll
    for (int rt = 0; rt < 4; ++rt)
#pragma unroll
      for (int ct = 0; ct < 2; ++ct)
        acc[rt][ct] = SWAP ? mfma16(b[ct], a[rt], acc[rt][ct])
                           : mfma16(a[rt], b[ct], acc[rt][ct]);
  }
}

__global__ __launch_bounds__(256, 3)
void winattn_kernel(const float* __restrict__ x,
                    const unsigned short* __restrict__ wqkvT,
                    const unsigned short* __restrict__ woutT,
                    const float* __restrict__ bias64,
                    const float* __restrict__ b_out,
                    float* __restrict__ out) {
  __shared__ unsigned short smem[SMEM_ELTS];

  const int tid = threadIdx.x;
  const int lane = tid & 63;
  const int w = tid >> 6;
  const int l15 = lane & 15;
  const int lq = lane >> 4;

  const int bid = blockIdx.x;
  const int win = bid & 255;
  const int img = bid >> 8;
  const int wy = win >> 4, wx = win & 15;

  unsigned short* x_lds  = smem;                 // phase 1-2: x; phase 3-4: oh
  unsigned short* oh_lds = smem;
  unsigned short* rt_buf = smem + OFF_RT + w * RT_ELEMS;   // wave-private

  const f32x4 zero4 = {0.f, 0.f, 0.f, 0.f};
  const size_t img_base = (size_t)img * 128 * 128 * 256;

  // ---------- phase 1: stage x window -> bf16 LDS (coalesced) ----------
  {
#pragma unroll
    for (int r = 0; r < 16; ++r) {
      int p = r * 4 + w;                 // pixel 0..63
      const float* src = x + img_base +
          (((size_t)(wy * 8 + (p >> 3)) * 128) + (wx * 8 + (p & 7))) * 256 + lane * 4;
      float4 v4 = *(const float4*)src;
      *(uint2*)&x_lds[p * XO + lane * 4] = pack4(v4.x, v4.y, v4.z, v4.w);
    }
  }
  __syncthreads();   // bar1

  // ---------- phase 2: q/k/v for this wave's 2 heads, dual-acc interleave ----------
  // qf/kf[rt][hh]: A/B-frag, (px rt*16+l15, feat hh*32+lq*8..+8)
  // vf[ft][h2][hh]: A-frag of vT, (feat hh*32+ft*16+l15, kv px h2*32+lq*8..+8)
  bf16x8 qf[4][2], kf[4][2], vf[2][2][2];

#define RT_QK(ACCV, DEST, HH)                                                   \
  _Pragma("unroll")                                                             \
  for (int h2 = 0; h2 < 2; ++h2) {                                              \
    _Pragma("unroll")                                                           \
    for (int rr = 0; rr < 2; ++rr)                                              \
      _Pragma("unroll")                                                         \
      for (int ct = 0; ct < 2; ++ct)                                            \
        *(uint2*)&rt_buf[(rr * 16 + l15) * RTS + ct * 16 + lq * 4] =            \
            pack4(ACCV[h2 * 2 + rr][ct][0], ACCV[h2 * 2 + rr][ct][1],           \
                  ACCV[h2 * 2 + rr][ct][2], ACCV[h2 * 2 + rr][ct][3]);          \
    _Pragma("unroll")                                                           \
    for (int rr = 0; rr < 2; ++rr)                                              \
      DEST[h2 * 2 + rr][HH] =                                                   \
          *(const bf16x8*)&rt_buf[(rr * 16 + l15) * RTS + lq * 8];              \
  }

#define RT_V(ACCV, HH)                                                          \
  _Pragma("unroll")                                                             \
  for (int h2 = 0; h2 < 2; ++h2) {                                              \
    _Pragma("unroll")                                                           \
    for (int rr = 0; rr < 2; ++rr)                                              \
      _Pragma("unroll")                                                         \
      for (int ct = 0; ct < 2; ++ct)                                            \
        *(uint2*)&rt_buf[(ct * 16 + l15) * RTS + rr * 16 + lq * 4] =            \
            pack4(ACCV[h2 * 2 + rr][ct][0], ACCV[h2 * 2 + rr][ct][1],           \
                  ACCV[h2 * 2 + rr][ct][2], ACCV[h2 * 2 + rr][ct][3]);          \
    _Pragma("unroll")                                                           \
    for (int ft = 0; ft < 2; ++ft)                                              \
      vf[ft][h2][HH] =                                                          \
          *(const bf16x8*)&rt_buf[(ft * 16 + l15) * RTS + lq * 8];              \
  }

  {
    f32x4 accA[4][2], accB[4][2];
    gemm32<true >(accA, x_lds, wqkvT,       w * 64 +  0, l15, lq);   // q hh0
    gemm32<true >(accB, x_lds, wqkvT, 256 + w * 64 +  0, l15, lq);   // k hh0
    RT_QK(accA, qf, 0)
    gemm32<true >(accA, x_lds, wqkvT,       w * 64 + 32, l15, lq);   // q hh1
    RT_QK(accB, kf, 0)
    gemm32<true >(accB, x_lds, wqkvT, 256 + w * 64 + 32, l15, lq);   // k hh1
    RT_QK(accA, qf, 1)
    gemm32<false>(accA, x_lds, wqkvT, 512 + w * 64 +  0, l15, lq);   // v hh0
    RT_QK(accB, kf, 1)
    gemm32<false>(accB, x_lds, wqkvT, 512 + w * 64 + 32, l15, lq);   // v hh1
    RT_V(accA, 0)
    RT_V(accB, 1)
  }
  __syncthreads();   // bar2: all x reads done -> oh region (overlays x) safe

  // ---------- phase 3: attention, software-pipelined over 8 (it,hh) iters ----------
  // COMPUTE_S(i): S^T = mfma(k,q), p = exp2(s*ES+bias), rowsum -> rinv.
#define COMPUTE_S(IT, HH, SV, RV)                                               \
  {                                                                             \
    f32x4 bias4[4];                                                             \
    _Pragma("unroll")                                                           \
    for (int jt = 0; jt < 4; ++jt)                                              \
      bias4[jt] = *(const f32x4*)&bias64[((IT) * 16 + l15) * 64 + jt * 16 + lq * 4]; \
    float rs = 0.f;                                                             \
    _Pragma("unroll")                                                           \
    for (int jt = 0; jt < 4; ++jt) {                                            \
      SV[jt] = mfma16(kf[jt][HH], qf[IT][HH], zero4);                           \
      _Pragma("unroll")                                                         \
      for (int r = 0; r < 4; ++r) {                                             \
        SV[jt][r] = __builtin_amdgcn_exp2f(SV[jt][r] * EXPSCALE + bias4[jt][r]);\
        rs += SV[jt][r];                                                        \
      }                                                                         \
    }                                                                           \
    rs += __shfl_xor(rs, 16);                                                   \
    rs += __shfl_xor(rs, 32);                                                   \
    RV = __builtin_amdgcn_rcpf(rs);                                             \
  }

  {
    f32x4 s[4];
    float rinv;
    COMPUTE_S(0, 0, s, rinv)
#pragma unroll
    for (int i = 0; i < 8; ++i) {
      const int it = i >> 1, hh = i & 1;
      // 1. P(i) -> wave-private scratch (P[q l15][kv]), packed b64
#pragma unroll
      for (int jt = 0; jt < 4; ++jt)
        *(uint2*)&rt_buf[l15 * PS + jt * 16 + lq * 4] =
            pack4(s[jt][0], s[jt][1], s[jt][2], s[jt][3]);

      // 2. S(i+1)+exp+rowsum fills the P round-trip gap
      f32x4 sn[4];
      float rinvn = 0.f;
      if (i < 7) {
        const int itn = (i + 1) >> 1, hhn = (i + 1) & 1;
        COMPUTE_S(itn, hhn, sn, rinvn)
      }

      // 3. P readback (in-order DS queue: waits for the write)
      const bf16x8 ap0 = *(const bf16x8*)&rt_buf[l15 * PS + lq * 8];
      const bf16x8 ap1 = *(const bf16x8*)&rt_buf[l15 * PS + 32 + lq * 8];

      // 4. oh^T = mfma(vT, P^T): D[feat ft*16+lq*4+r][q px it*16+l15]
      f32x4 o0 = mfma16(vf[0][0][hh], ap0, zero4);
      o0 = mfma16(vf[0][1][hh], ap1, o0);
      f32x4 o1 = mfma16(vf[1][0][hh], ap0, zero4);
      o1 = mfma16(vf[1][1][hh], ap1, o1);

      // 5. normalize + stage oh (shared region), packed b64
      *(uint2*)&oh_lds[(it * 16 + l15) * XO + w * 64 + hh * 32 + lq * 4] =
          pack4(o0[0] * rinv, o0[1] * rinv, o0[2] * rinv, o0[3] * rinv);
      *(uint2*)&oh_lds[(it * 16 + l15) * XO + w * 64 + hh * 32 + 16 + lq * 4] =
          pack4(o1[0] * rinv, o1[1] * rinv, o1[2] * rinv, o1[3] * rinv);

      // 6. shift pipeline
      if (i < 7) {
#pragma unroll
        for (int jt = 0; jt < 4; ++jt) s[jt] = sn[jt];
        rinv = rinvn;
      }
    }
  }
  __syncthreads();   // bar3: oh complete

  // ---------- phase 4: out-proj K=256 GEMM (swapped), ping-pong prefetch ----------
  {
    f32x4 ACC[4][4];
#pragma unroll
    for (int rt = 0; rt < 4; ++rt)
#pragma unroll
      for (int ct = 0; ct < 4; ++ct) ACC[rt][ct] = zero4;

    bf16x8 ag[2][4], bg[2][4];
#pragma unroll
    for (int rt = 0; rt < 4; ++rt)
      ag[0][rt] = *(const bf16x8*)&oh_lds[(rt * 16 + l15) * XO + lq * 8];
#pragma unroll
    for (int ct = 0; ct < 4; ++ct)
      bg[0][ct] = *(const bf16x8*)&woutT[(((w * 4 + ct) * 8 + 0) * 4 + lq) * 128 + l15 * 8];

#pragma unroll
    for (int kk = 0; kk < 8; ++kk) {
      const int c = kk & 1, n = c ^ 1;
      if (kk < 7) {
#pragma unroll
        for (int rt = 0; rt < 4; ++rt)
          ag[n][rt] = *(const bf16x8*)&oh_lds[(rt * 16 + l15) * XO + (kk + 1) * 32 + lq * 8];
#pragma unroll
        for (int ct = 0; ct < 4; ++ct)
          bg[n][ct] = *(const bf16x8*)&woutT[(((w * 4 + ct) * 8 + kk + 1) * 4 + lq) * 128 + l15 * 8];
      }
#pragma unroll
      for (int rt = 0; rt < 4; ++rt)
#pragma unroll
        for (int ct = 0; ct < 4; ++ct)
          ACC[rt][ct] = mfma16(bg[c][ct], ag[c][rt], ACC[rt][ct]);   // D[ofeat][px]
    }

    // epilogue: D rows = ofeat w*64+ct*16+lq*4+r, cols = px rt*16+l15
#pragma unroll
    for (int rt = 0; rt < 4; ++rt) {
      const int p = rt * 16 + l15;
      float* orow = out + img_base +
          (((size_t)(wy * 8 + (p >> 3)) * 128) + (wx * 8 + (p & 7))) * 256;
#pragma unroll
      for (int ct = 0; ct < 4; ++ct) {
        const int n0 = w * 64 + ct * 16 + lq * 4;
        const f32x4 bo4 = *(const f32x4*)&b_out[n0];
        f32x4 st;
#pragma unroll
        for (int r = 0; r < 4; ++r) st[r] = ACC[rt][ct][r] + bo4[r];
        *(f32x4*)(orow + n0) = st;
      }
    }
  }
}

extern "C" void kernel_launch(void* const* d_in, const int* in_sizes, int n_in,
                              void* d_out, int out_size, void* d_ws, size_t ws_size,
                              hipStream_t stream) {
  const float* x       = (const float*)d_in[0];
  const float* w_qkv   = (const float*)d_in[1];
  const float* pos_emb = (const float*)d_in[2];
  const float* w_out   = (const float*)d_in[3];
  const float* b_out   = (const float*)d_in[4];
  float* out = (float*)d_out;

  unsigned short* wqkvT = (unsigned short*)d_ws;
  unsigned short* woutT = wqkvT + 768 * 256;
  float* bias64 = (float*)(woutT + 256 * 256);

  prep_kernel<<<96, 256, 0, stream>>>(w_qkv, w_out, pos_emb, wqkvT, woutT, bias64);
  winattn_kernel<<<2048, 256, 0, stream>>>(x, wqkvT, woutT, bias64, b_out, out);
}

// Round 12
// 121.432 us; speedup vs baseline: 1.3185x; 1.0897x over previous
//
#include <hip/hip_runtime.h>
#include <hip/hip_bf16.h>

// Fused Swin window attention for MI355X (gfx950) — round 12: r9 + isolated ILP.
// r11 bundled {phase2 dual-acc, phase3 pipeline, phase4 ping-pong} and regressed
// (FETCH+15MB/WRITE+32MB spills): dual-acc's 64 extra live f32 blew the AGPR
// headroom the compiler uses to park qf/kf/vf (VGPR_Count 84 in both r9/r11 —
// fragments live in AGPRs via v_accvgpr, spills only when THAT overflows).
// r12 keeps r9's phase 1+2 VERBATIM (no-spill config) and grafts only the two
// register-light pieces, both correctness-verified in r11:
//   * phase 3: software pipeline — S(i+1)+exp+rowsum covers P(i)'s in-order-DS
//     write->read round-trip (~150 cyc/iter x 8 iters).
//   * phase 4: ping-pong prefetch — kk+1 a/b frag loads issued under kk's 16
//     MFMAs (covers ~200cyc L2 latency x 8 k-steps).
// Tripwire: FETCH/WRITE must return to ~72/~131 MB (else phase-3 also spills).

typedef __attribute__((ext_vector_type(8))) short bf16x8;
typedef __attribute__((ext_vector_type(4))) float f32x4;

__device__ __forceinline__ f32x4 mfma16(bf16x8 a, bf16x8 b, f32x4 c) {
  return __builtin_amdgcn_mfma_f32_16x16x32_bf16(a, b, c, 0, 0, 0);
}

__device__ __forceinline__ unsigned short f2bf(float f) {
  __hip_bfloat16 h = __float2bfloat16(f);
  return *reinterpret_cast<unsigned short*>(&h);
}

__device__ __forceinline__ uint2 pack4(float a, float b, float c, float d) {
  union { unsigned short u[4]; uint2 v; } pk;
  pk.u[0] = f2bf(a); pk.u[1] = f2bf(b); pk.u[2] = f2bf(c); pk.u[3] = f2bf(d);
  return pk.v;
}

#define LOG2E 1.4426950408889634f
#define EXPSCALE (0.17677669529663687f * 1.4426950408889634f)

// LDS layout (ushort elements); row strides multiples of 8 elem (16B) for b128.
#define XO  264           // x / oh region row stride (64 rows)
#define RTS 40            // per-wave RT scratch row stride (32 rows used)
#define PS  72            // P scratch row stride (16 rows)
#define RT_ELEMS 1280     // per-wave scratch: 32x40 (covers P's 16x72=1152)
#define OFF_RT 16896      // 64*264
#define SMEM_ELTS 22016   // 16896 + 4*1280 = 44,032 B -> 3 blocks/CU

// Weight tiled layout: elem(n,k) -> ((((n>>4)*8+(k>>5))*4+((k>>3)&3))*16+(n&15))*8+(k&7)
__global__ void prep_kernel(const float* __restrict__ w_qkv,
                            const float* __restrict__ w_out,
                            const float* __restrict__ pos_emb,
                            unsigned short* __restrict__ wqkvT,
                            unsigned short* __restrict__ woutT,
                            float* __restrict__ bias64) {
  const int stride = gridDim.x * blockDim.x;
  const int tid = blockIdx.x * blockDim.x + threadIdx.x;
  for (int i = tid; i < 768 * 256; i += stride) {
    int n = i >> 8, k = i & 255;
    int off = ((((n >> 4) * 8 + (k >> 5)) * 4 + ((k >> 3) & 3)) * 16 + (n & 15)) * 8 + (k & 7);
    wqkvT[off] = f2bf(w_qkv[k * 768 + n]);
  }
  for (int i = tid; i < 256 * 256; i += stride) {
    int n = i >> 8, k = i & 255;
    int off = ((((n >> 4) * 8 + (k >> 5)) * 4 + ((k >> 3) & 3)) * 16 + (n & 15)) * 8 + (k & 7);
    woutT[off] = f2bf(w_out[k * 256 + n]);
  }
  for (int i = tid; i < 64 * 64; i += stride) {
    int a = i >> 6, b = i & 63;
    int d0 = (b >> 3) - (a >> 3) + 7;
    int d1 = (b & 7) - (a & 7) + 7;
    bias64[i] = pos_emb[d0 * 15 + d1] * LOG2E;   // pre-scaled for exp2
  }
}

// 64px x 32col GEMM slice. SWAP=true: acc = mfma(w, x) -> (feat row, px col).
// SWAP=false: acc = mfma(x, w) -> (px row, feat col).
template <bool SWAP>
__device__ __forceinline__ void gemm32(f32x4 (&acc)[4][2],
                                       const unsigned short* __restrict__ a_lds,
                                       const unsigned short* __restrict__ wT,
                                       int col0, int l15, int lq) {
  const f32x4 zero4 = {0.f, 0.f, 0.f, 0.f};
#pragma unroll
  for (int rt = 0; rt < 4; ++rt)
#pragma unroll
    for (int ct = 0; ct < 2; ++ct) acc[rt][ct] = zero4;
#pragma unroll
  for (int kk = 0; kk < 8; ++kk) {
    bf16x8 a[4], b[2];
#pragma unroll
    for (int rt = 0; rt < 4; ++rt)
      a[rt] = *(const bf16x8*)&a_lds[(rt * 16 + l15) * XO + kk * 32 + lq * 8];
#pragma unroll
    for (int ct = 0; ct < 2; ++ct)
      b[ct] = *(const bf16x8*)&wT[((((col0 >> 4) + ct) * 8 + kk) * 4 + lq) * 128 + l15 * 8];
#pragma unroll
    for (int rt = 0; rt < 4; ++rt)
#pragma unroll
      for (int ct = 0; ct < 2; ++ct)
        acc[rt][ct] = SWAP ? mfma16(b[ct], a[rt], acc[rt][ct])
                           : mfma16(a[rt], b[ct], acc[rt][ct]);
  }
}

__global__ __launch_bounds__(256, 3)
void winattn_kernel(const float* __restrict__ x,
                    const unsigned short* __restrict__ wqkvT,
                    const unsigned short* __restrict__ woutT,
                    const float* __restrict__ bias64,
                    const float* __restrict__ b_out,
                    float* __restrict__ out) {
  __shared__ unsigned short smem[SMEM_ELTS];

  const int tid = threadIdx.x;
  const int lane = tid & 63;
  const int w = tid >> 6;
  const int l15 = lane & 15;
  const int lq = lane >> 4;

  const int bid = blockIdx.x;
  const int win = bid & 255;
  const int img = bid >> 8;
  const int wy = win >> 4, wx = win & 15;

  unsigned short* x_lds  = smem;                 // phase 1-2: x; phase 3-4: oh
  unsigned short* oh_lds = smem;
  unsigned short* rt_buf = smem + OFF_RT + w * RT_ELEMS;   // wave-private

  const f32x4 zero4 = {0.f, 0.f, 0.f, 0.f};
  const size_t img_base = (size_t)img * 128 * 128 * 256;

  // ---------- phase 1: stage x window -> bf16 LDS (coalesced) ----------
  {
#pragma unroll
    for (int r = 0; r < 16; ++r) {
      int p = r * 4 + w;                 // pixel 0..63
      const float* src = x + img_base +
          (((size_t)(wy * 8 + (p >> 3)) * 128) + (wx * 8 + (p & 7))) * 256 + lane * 4;
      float4 v4 = *(const float4*)src;
      *(uint2*)&x_lds[p * XO + lane * 4] = pack4(v4.x, v4.y, v4.z, v4.w);
    }
  }
  __syncthreads();   // bar1

  // ---------- phase 2: q/k/v for this wave's 2 heads (r9 verbatim) ----------
  // qf/kf[rt][hh]: A/B-frag, (px rt*16+l15, feat hh*32+lq*8..+8)
  // vf[ft][h2][hh]: A-frag of vT, (feat hh*32+ft*16+l15, kv px h2*32+lq*8..+8)
  bf16x8 qf[4][2], kf[4][2], vf[2][2][2];
  {
    f32x4 acc[4][2];
#pragma unroll
    for (int hh = 0; hh < 2; ++hh) {    // q chunk (swapped: feat rows, px cols)
      gemm32<true>(acc, x_lds, wqkvT, w * 64 + hh * 32, l15, lq);
#pragma unroll
      for (int h2 = 0; h2 < 2; ++h2) {  // px halves through RT scratch
#pragma unroll
        for (int rr = 0; rr < 2; ++rr)
#pragma unroll
          for (int ct = 0; ct < 2; ++ct)
            *(uint2*)&rt_buf[(rr * 16 + l15) * RTS + ct * 16 + lq * 4] =
                pack4(acc[h2 * 2 + rr][ct][0], acc[h2 * 2 + rr][ct][1],
                      acc[h2 * 2 + rr][ct][2], acc[h2 * 2 + rr][ct][3]);
#pragma unroll
        for (int rr = 0; rr < 2; ++rr)
          qf[h2 * 2 + rr][hh] = *(const bf16x8*)&rt_buf[(rr * 16 + l15) * RTS + lq * 8];
      }
    }
#pragma unroll
    for (int hh = 0; hh < 2; ++hh) {    // k chunk
      gemm32<true>(acc, x_lds, wqkvT, 256 + w * 64 + hh * 32, l15, lq);
#pragma unroll
      for (int h2 = 0; h2 < 2; ++h2) {
#pragma unroll
        for (int rr = 0; rr < 2; ++rr)
#pragma unroll
          for (int ct = 0; ct < 2; ++ct)
            *(uint2*)&rt_buf[(rr * 16 + l15) * RTS + ct * 16 + lq * 4] =
                pack4(acc[h2 * 2 + rr][ct][0], acc[h2 * 2 + rr][ct][1],
                      acc[h2 * 2 + rr][ct][2], acc[h2 * 2 + rr][ct][3]);
#pragma unroll
        for (int rr = 0; rr < 2; ++rr)
          kf[h2 * 2 + rr][hh] = *(const bf16x8*)&rt_buf[(rr * 16 + l15) * RTS + lq * 8];
      }
    }
#pragma unroll
    for (int hh = 0; hh < 2; ++hh) {    // v chunk (normal: px rows, feat cols)
      gemm32<false>(acc, x_lds, wqkvT, 512 + w * 64 + hh * 32, l15, lq);
#pragma unroll
      for (int h2 = 0; h2 < 2; ++h2) {  // kv-px halves; transpose via RT
#pragma unroll
        for (int rr = 0; rr < 2; ++rr)
#pragma unroll
          for (int ct = 0; ct < 2; ++ct)
            *(uint2*)&rt_buf[(ct * 16 + l15) * RTS + rr * 16 + lq * 4] =
                pack4(acc[h2 * 2 + rr][ct][0], acc[h2 * 2 + rr][ct][1],
                      acc[h2 * 2 + rr][ct][2], acc[h2 * 2 + rr][ct][3]);
#pragma unroll
        for (int ft = 0; ft < 2; ++ft)
          vf[ft][h2][hh] = *(const bf16x8*)&rt_buf[(ft * 16 + l15) * RTS + lq * 8];
      }
    }
  }
  __syncthreads();   // bar2: all x reads done -> oh region (overlays x) safe

  // ---------- phase 3: attention, software-pipelined over 8 (it,hh) iters ----------
#define COMPUTE_S(IT, HH, SV, RV)                                               \
  {                                                                             \
    f32x4 bias4[4];                                                             \
    _Pragma("unroll")                                                           \
    for (int jt = 0; jt < 4; ++jt)                                              \
      bias4[jt] = *(const f32x4*)&bias64[((IT) * 16 + l15) * 64 + jt * 16 + lq * 4]; \
    float rs = 0.f;                                                             \
    _Pragma("unroll")                                                           \
    for (int jt = 0; jt < 4; ++jt) {                                            \
      SV[jt] = mfma16(kf[jt][HH], qf[IT][HH], zero4);                           \
      _Pragma("unroll")                                                         \
      for (int r = 0; r < 4; ++r) {                                             \
        SV[jt][r] = __builtin_amdgcn_exp2f(SV[jt][r] * EXPSCALE + bias4[jt][r]);\
        rs += SV[jt][r];                                                        \
      }                                                                         \
    }                                                                           \
    rs += __shfl_xor(rs, 16);                                                   \
    rs += __shfl_xor(rs, 32);                                                   \
    RV = __builtin_amdgcn_rcpf(rs);                                             \
  }

  {
    f32x4 s[4];
    float rinv;
    COMPUTE_S(0, 0, s, rinv)
#pragma unroll
    for (int i = 0; i < 8; ++i) {
      const int it = i >> 1, hh = i & 1;
      // 1. P(i) -> wave-private scratch (P[q l15][kv]), packed b64
#pragma unroll
      for (int jt = 0; jt < 4; ++jt)
        *(uint2*)&rt_buf[l15 * PS + jt * 16 + lq * 4] =
            pack4(s[jt][0], s[jt][1], s[jt][2], s[jt][3]);

      // 2. S(i+1)+exp+rowsum fills the P round-trip gap
      f32x4 sn[4];
      float rinvn = 0.f;
      if (i < 7) {
        const int itn = (i + 1) >> 1, hhn = (i + 1) & 1;
        COMPUTE_S(itn, hhn, sn, rinvn)
      }

      // 3. P readback (in-order DS queue: waits for the write)
      const bf16x8 ap0 = *(const bf16x8*)&rt_buf[l15 * PS + lq * 8];
      const bf16x8 ap1 = *(const bf16x8*)&rt_buf[l15 * PS + 32 + lq * 8];

      // 4. oh^T = mfma(vT, P^T): D[feat ft*16+lq*4+r][q px it*16+l15]
      f32x4 o0 = mfma16(vf[0][0][hh], ap0, zero4);
      o0 = mfma16(vf[0][1][hh], ap1, o0);
      f32x4 o1 = mfma16(vf[1][0][hh], ap0, zero4);
      o1 = mfma16(vf[1][1][hh], ap1, o1);

      // 5. normalize + stage oh (shared region), packed b64
      *(uint2*)&oh_lds[(it * 16 + l15) * XO + w * 64 + hh * 32 + lq * 4] =
          pack4(o0[0] * rinv, o0[1] * rinv, o0[2] * rinv, o0[3] * rinv);
      *(uint2*)&oh_lds[(it * 16 + l15) * XO + w * 64 + hh * 32 + 16 + lq * 4] =
          pack4(o1[0] * rinv, o1[1] * rinv, o1[2] * rinv, o1[3] * rinv);

      // 6. shift pipeline
      if (i < 7) {
#pragma unroll
        for (int jt = 0; jt < 4; ++jt) s[jt] = sn[jt];
        rinv = rinvn;
      }
    }
  }
  __syncthreads();   // bar3: oh complete

  // ---------- phase 4: out-proj K=256 GEMM (swapped), ping-pong prefetch ----------
  {
    f32x4 ACC[4][4];
#pragma unroll
    for (int rt = 0; rt < 4; ++rt)
#pragma unroll
      for (int ct = 0; ct < 4; ++ct) ACC[rt][ct] = zero4;

    bf16x8 ag[2][4], bg[2][4];
#pragma unroll
    for (int rt = 0; rt < 4; ++rt)
      ag[0][rt] = *(const bf16x8*)&oh_lds[(rt * 16 + l15) * XO + lq * 8];
#pragma unroll
    for (int ct = 0; ct < 4; ++ct)
      bg[0][ct] = *(const bf16x8*)&woutT[(((w * 4 + ct) * 8 + 0) * 4 + lq) * 128 + l15 * 8];

#pragma unroll
    for (int kk = 0; kk < 8; ++kk) {
      const int c = kk & 1, n = c ^ 1;
      if (kk < 7) {
#pragma unroll
        for (int rt = 0; rt < 4; ++rt)
          ag[n][rt] = *(const bf16x8*)&oh_lds[(rt * 16 + l15) * XO + (kk + 1) * 32 + lq * 8];
#pragma unroll
        for (int ct = 0; ct < 4; ++ct)
          bg[n][ct] = *(const bf16x8*)&woutT[(((w * 4 + ct) * 8 + kk + 1) * 4 + lq) * 128 + l15 * 8];
      }
#pragma unroll
      for (int rt = 0; rt < 4; ++rt)
#pragma unroll
        for (int ct = 0; ct < 4; ++ct)
          ACC[rt][ct] = mfma16(bg[c][ct], ag[c][rt], ACC[rt][ct]);   // D[ofeat][px]
    }

    // epilogue: D rows = ofeat w*64+ct*16+lq*4+r, cols = px rt*16+l15
#pragma unroll
    for (int rt = 0; rt < 4; ++rt) {
      const int p = rt * 16 + l15;
      float* orow = out + img_base +
          (((size_t)(wy * 8 + (p >> 3)) * 128) + (wx * 8 + (p & 7))) * 256;
#pragma unroll
      for (int ct = 0; ct < 4; ++ct) {
        const int n0 = w * 64 + ct * 16 + lq * 4;
        const f32x4 bo4 = *(const f32x4*)&b_out[n0];
        f32x4 st;
#pragma unroll
        for (int r = 0; r < 4; ++r) st[r] = ACC[rt][ct][r] + bo4[r];
        *(f32x4*)(orow + n0) = st;
      }
    }
  }
}

extern "C" void kernel_launch(void* const* d_in, const int* in_sizes, int n_in,
                              void* d_out, int out_size, void* d_ws, size_t ws_size,
                              hipStream_t stream) {
  const float* x       = (const float*)d_in[0];
  const float* w_qkv   = (const float*)d_in[1];
  const float* pos_emb = (const float*)d_in[2];
  const float* w_out   = (const float*)d_in[3];
  const float* b_out   = (const float*)d_in[4];
  float* out = (float*)d_out;

  unsigned short* wqkvT = (unsigned short*)d_ws;
  unsigned short* woutT = wqkvT + 768 * 256;
  float* bias64 = (float*)(woutT + 256 * 256);

  prep_kernel<<<96, 256, 0, stream>>>(w_qkv, w_out, pos_emb, wqkvT, woutT, bias64);
  winattn_kernel<<<2048, 256, 0, stream>>>(x, wqkvT, woutT, bias64, b_out, out);
}